// Round 9
// baseline (446.015 us; speedup 1.0000x reference)
//
#include <hip/hip_runtime.h>
#include <hip/hip_bf16.h>
#include <stdint.h>

// TemporalAttention: x[B,T,C] -> qkv proj -> causal MHA -> out proj.
// B=4 T=2048 C=1024 H=16 D=64. Inputs fp32, output fp32; internal bf16 MFMA.
//
// R8 was a compile error (__hip_bfloat162 not trivially copyable for
// bit_cast); pk4 now element-wise f2bf. Round content unchanged from R8:
// (a) register-prefetch double-buffer of K/V staging, (b) merged A/B tile
// processing sharing kf/vf frag loads, (c) fences removed + per-tile sP,
// (d) exp2-domain softmax.

using bf16 = __hip_bfloat16;
typedef __attribute__((ext_vector_type(8))) __bf16 bf16x8;
typedef __attribute__((ext_vector_type(8))) unsigned short u16x8;
typedef __attribute__((ext_vector_type(4))) unsigned short u16x4;
typedef __attribute__((ext_vector_type(4))) float f32x4;
typedef unsigned short ushort_t;

#define MFMA16(a, b, c) __builtin_amdgcn_mfma_f32_16x16x32_bf16((a), (b), (c), 0, 0, 0)
#define EXP2(x) __builtin_amdgcn_exp2f(x)
#define SCL 0.1803368801f  // (1/sqrt(64)) * log2(e)

__device__ __forceinline__ bf16x8 ld_frag(const ushort_t* p) {
  const u16x8 u = *(const u16x8*)p;
  return __builtin_bit_cast(bf16x8, u);
}

__device__ __forceinline__ ushort_t f2bf(float f) {
  return __builtin_bit_cast(ushort_t, __float2bfloat16(f));
}

__device__ __forceinline__ u16x4 pk4(const f32x4 v) {
  u16x4 r;
  r[0] = f2bf(v[0]); r[1] = f2bf(v[1]); r[2] = f2bf(v[2]); r[3] = f2bf(v[3]);
  return r;
}

// async global->LDS, 16B/lane; lds base wave-uniform, lane l -> base+l*16.
__device__ __forceinline__ void gl2lds16(const void* g, void* lds) {
  __builtin_amdgcn_global_load_lds((const __attribute__((address_space(1))) void*)g,
                                   (__attribute__((address_space(3))) void*)lds,
                                   16, 0, 0);
}

// ---------------------------------------------------------------------------
// Dtype detector (hedge; fp32 established). flag=1 -> fp32.
// ---------------------------------------------------------------------------
__global__ void detect_dtype(const ushort_t* __restrict__ x, int* __restrict__ flag) {
  __shared__ int red[256];
  const int tid = threadIdx.x;
  int cnt = 0;
  for (int i = tid; i < 4096; i += 256) {
    const int e = (x[i] & 0x7FFF) >> 7;
    cnt += (e >= 117 && e <= 133) ? 1 : 0;
  }
  red[tid] = cnt;
  __syncthreads();
  for (int s = 128; s > 0; s >>= 1) {
    if (tid < s) red[tid] += red[tid + s];
    __syncthreads();
  }
  if (tid == 0) *flag = (red[0] < 3072) ? 1 : 0;
}

// ---------------------------------------------------------------------------
// fp32 -> bf16 (or copy if flag==0). n multiple of 2048.
// ---------------------------------------------------------------------------
__global__ void cvt_to_bf16(const void* __restrict__ in, ushort_t* __restrict__ out,
                            int n, const int* __restrict__ flag) {
  const int i = (blockIdx.x * 256 + threadIdx.x) * 8;
  if (i >= n) return;
  if (*flag) {
    const float* p = (const float*)in + i;
    const float4 f0 = *(const float4*)p;
    const float4 f1 = *(const float4*)(p + 4);
    u16x8 u;
    u[0] = f2bf(f0.x); u[1] = f2bf(f0.y); u[2] = f2bf(f0.z); u[3] = f2bf(f0.w);
    u[4] = f2bf(f1.x); u[5] = f2bf(f1.y); u[6] = f2bf(f1.z); u[7] = f2bf(f1.w);
    *(u16x8*)(out + i) = u;
  } else {
    *(u16x8*)(out + i) = *(const u16x8*)((const ushort_t*)in + i);
  }
}

// ---------------------------------------------------------------------------
// NT GEMM (unchanged from R7): 128x128 tile, 4 waves 2x2, BK=32, gl2lds.
// EPI==0: fp32 store. EPI==1: scatter q/k [B,H,T,D], V transposed [B,H,D,T].
// ---------------------------------------------------------------------------
template <int EPI>
__global__ __launch_bounds__(256, 2)
void gemm_nt(const ushort_t* __restrict__ A, const void* __restrict__ Bw,
             const int* __restrict__ flag, int bExt,
             float* __restrict__ C0, ushort_t* __restrict__ Qo,
             ushort_t* __restrict__ Ko, ushort_t* __restrict__ Vt,
             int M, int N, int Kd) {
  __shared__ ushort_t sA[128 * 32];
  __shared__ ushort_t sB[128 * 32];
  const int tid = threadIdx.x;
  const int wave = tid >> 6, lane = tid & 63;
  const int quad = lane >> 4, l16 = lane & 15;
  const int wm = wave >> 1, wn = wave & 1;
  const long m0 = (long)blockIdx.y * 128;
  const long n0 = (long)blockIdx.x * 128;
  const int bF = bExt ? *flag : 0;

  f32x4 acc[4][4];
#pragma unroll
  for (int i = 0; i < 4; ++i)
#pragma unroll
    for (int j = 0; j < 4; ++j) acc[i][j] = (f32x4){0.f, 0.f, 0.f, 0.f};

  for (int k0 = 0; k0 < Kd; k0 += 32) {
#pragma unroll
    for (int j = 0; j < 2; ++j) {
      const int chunk = wave * 2 + j;
      const int idx = chunk * 64 + lane;
      const int r = idx >> 2, c = idx & 3;
      gl2lds16(A + (m0 + r) * (long)Kd + k0 + c * 8, (char*)sA + chunk * 1024);
    }
    if (!bF) {
#pragma unroll
      for (int j = 0; j < 2; ++j) {
        const int chunk = wave * 2 + j;
        const int idx = chunk * 64 + lane;
        const int r = idx >> 2, c = idx & 3;
        gl2lds16((const ushort_t*)Bw + (n0 + r) * (long)Kd + k0 + c * 8,
                 (char*)sB + chunk * 1024);
      }
    } else {
#pragma unroll
      for (int t2 = 0; t2 < 2; ++t2) {
        const int idx = t2 * 256 + tid;
        const int r = idx >> 2, c = idx & 3;
        const float* p = (const float*)Bw + (n0 + r) * (long)Kd + k0 + c * 8;
        const float4 f0 = *(const float4*)p;
        const float4 f1 = *(const float4*)(p + 4);
        u16x8 u;
        u[0] = f2bf(f0.x); u[1] = f2bf(f0.y); u[2] = f2bf(f0.z); u[3] = f2bf(f0.w);
        u[4] = f2bf(f1.x); u[5] = f2bf(f1.y); u[6] = f2bf(f1.z); u[7] = f2bf(f1.w);
        *(u16x8*)&sB[r * 32 + c * 8] = u;
      }
    }
    __syncthreads();
    bf16x8 af[4], bfr[4];
#pragma unroll
    for (int i = 0; i < 4; ++i) {
      const int r = wm * 64 + i * 16 + l16;
      af[i] = ld_frag(&sA[r * 32 + quad * 8]);
    }
#pragma unroll
    for (int i = 0; i < 4; ++i) {
      const int r = wn * 64 + i * 16 + l16;
      bfr[i] = ld_frag(&sB[r * 32 + quad * 8]);
    }
#pragma unroll
    for (int i = 0; i < 4; ++i)
#pragma unroll
      for (int j = 0; j < 4; ++j) acc[i][j] = MFMA16(af[i], bfr[j], acc[i][j]);
    __syncthreads();
  }

#pragma unroll
  for (int i = 0; i < 4; ++i) {
#pragma unroll
    for (int j = 0; j < 4; ++j) {
      if (EPI == 0) {
#pragma unroll
        for (int reg = 0; reg < 4; ++reg) {
          const long m = m0 + wm * 64 + i * 16 + quad * 4 + reg;
          const long n = n0 + wn * 64 + j * 16 + l16;
          C0[m * N + n] = acc[i][j][reg];
        }
      } else {
        const long n = n0 + wn * 64 + j * 16 + l16;
        const int which = (int)(n >> 10);
        const int h = (int)((n >> 6) & 15);
        const int d = (int)(n & 63);
        const long mbase = m0 + wm * 64 + i * 16 + quad * 4;
        const long b = mbase >> 11;
        const long tb = mbase & 2047;
        if (which == 2) {
          *(u16x4*)&Vt[((b * 16 + h) * 64 + d) * 2048 + tb] = pk4(acc[i][j]);
        } else {
          ushort_t* dst = (which == 0) ? Qo : Ko;
#pragma unroll
          for (int reg = 0; reg < 4; ++reg)
            dst[((b * 16 + h) * 2048 + tb + reg) * 64 + d] = f2bf(acc[i][j][reg]);
        }
      }
    }
  }
}

// ---------------------------------------------------------------------------
// Flash attention (causal), S^T/O^T, merged A/B pair per kv tile.
// exp2-domain online softmax; per-tile sP regions; no fences (RAW on sP is
// compiler-ordered; WAR covered by staging barrier).
// ---------------------------------------------------------------------------
#define RS 72  // LDS row stride in ushorts (64 + 16B pad)

__device__ __forceinline__ void softmax_upd(f32x4 s[4], int kb, int qg,
                                            float& m_i, float& l_i, f32x4* oacc,
                                            ushort_t* sPw, int quad, int l16) {
  float rmax = -1e30f;
#pragma unroll
  for (int nt = 0; nt < 4; ++nt) {
#pragma unroll
    for (int reg = 0; reg < 4; ++reg) {
      float v = s[nt][reg] * SCL;  // log2-domain scaled scores
      if (kb + nt * 16 + reg > qg) v = -1e30f;
      s[nt][reg] = v;
      rmax = fmaxf(rmax, v);
    }
  }
  rmax = fmaxf(rmax, __shfl_xor(rmax, 16, 64));
  rmax = fmaxf(rmax, __shfl_xor(rmax, 32, 64));
  const float mnew = fmaxf(m_i, rmax);
  float rs = 0.f;
#pragma unroll
  for (int nt = 0; nt < 4; ++nt) {
#pragma unroll
    for (int reg = 0; reg < 4; ++reg) {
      const float p = EXP2(s[nt][reg] - mnew);
      s[nt][reg] = p;
      rs += p;
    }
  }
  rs += __shfl_xor(rs, 16, 64);
  rs += __shfl_xor(rs, 32, 64);
  const float alpha = EXP2(m_i - mnew);
  l_i = l_i * alpha + rs;
  m_i = mnew;
#pragma unroll
  for (int dt = 0; dt < 4; ++dt) oacc[dt] *= alpha;
#pragma unroll
  for (int nt = 0; nt < 4; ++nt)
    *(u16x4*)&sPw[l16 * RS + nt * 16 + quad * 4] = pk4(s[nt]);
}

__global__ __launch_bounds__(256, 4)
void attn_causal(const ushort_t* __restrict__ Qg, const ushort_t* __restrict__ Kg,
                 const ushort_t* __restrict__ Vt, ushort_t* __restrict__ Yg) {
  __shared__ ushort_t sK[64 * RS];
  __shared__ ushort_t sV[64 * RS];
  __shared__ ushort_t sPQ[64 * RS];   // Q staging, then per-wave sP for tile A
  __shared__ ushort_t sPB[64 * RS];   // per-wave sP for tile B
  const int tid = threadIdx.x;
  const int wave = tid >> 6, lane = tid & 63;
  const int quad = lane >> 4, l16 = lane & 15;
  const int qx = blockIdx.x, bh = blockIdx.y;
  const int qtA = qx, qtB = 31 - qx;
  const size_t base = (size_t)bh * 2048 * 64;
  ushort_t* sPwA = sPQ + wave * 16 * RS;
  ushort_t* sPwB = sPB + wave * 16 * RS;

  // stage Q tiles -> qfA/qfB frags (sPQ reused)
  bf16x8 qfA[2], qfB[2];
#pragma unroll
  for (int tile = 0; tile < 2; ++tile) {
    const int qt = tile ? qtB : qtA;
#pragma unroll
    for (int t2 = 0; t2 < 2; ++t2) {
      const int idx = t2 * 256 + tid;
      const int r = idx >> 3, c = idx & 7;
      *(u16x8*)&sPQ[r * RS + c * 8] =
          *(const u16x8*)(Qg + base + (size_t)(qt * 64 + r) * 64 + c * 8);
    }
    __syncthreads();
#pragma unroll
    for (int kk = 0; kk < 2; ++kk) {
      const bf16x8 f = ld_frag(&sPQ[(wave * 16 + l16) * RS + (kk * 4 + quad) * 8]);
      if (tile) qfB[kk] = f; else qfA[kk] = f;
    }
    __syncthreads();
  }

  float mA = -1e30f, lA = 0.f, mB = -1e30f, lB = 0.f;
  f32x4 oA[4], oB[4];
#pragma unroll
  for (int dt = 0; dt < 4; ++dt) {
    oA[dt] = (f32x4){0.f, 0.f, 0.f, 0.f};
    oB[dt] = (f32x4){0.f, 0.f, 0.f, 0.f};
  }
  const int qgA = qtA * 64 + wave * 16 + l16;
  const int qgB = qtB * 64 + wave * 16 + l16;

  // prefetch kv=0 staging chunks into registers
  const int r0 = tid >> 3, c0 = tid & 7;            // t2=0
  const int r1 = (256 + tid) >> 3, c1 = tid & 7;    // t2=1
  u16x8 rk0, rk1, rv0, rv1;
  rk0 = *(const u16x8*)(Kg + base + (size_t)r0 * 64 + c0 * 8);
  rk1 = *(const u16x8*)(Kg + base + (size_t)r1 * 64 + c1 * 8);
  rv0 = *(const u16x8*)(Vt + base + (size_t)r0 * 2048 + c0 * 8);
  rv1 = *(const u16x8*)(Vt + base + (size_t)r1 * 2048 + c1 * 8);

  for (int kv = 0; kv <= qtB; ++kv) {
    __syncthreads();  // all waves done reading prev sK/sV
    *(u16x8*)&sK[r0 * RS + c0 * 8] = rk0;
    *(u16x8*)&sK[r1 * RS + c1 * 8] = rk1;
    *(u16x8*)&sV[r0 * RS + c0 * 8] = rv0;
    *(u16x8*)&sV[r1 * RS + c1 * 8] = rv1;
    __syncthreads();
    if (kv < qtB) {  // prefetch next tile; overlaps with compute below
      const size_t kb2 = base + (size_t)(kv + 1) * 64 * 64;
      rk0 = *(const u16x8*)(Kg + kb2 + (size_t)r0 * 64 + c0 * 8);
      rk1 = *(const u16x8*)(Kg + kb2 + (size_t)r1 * 64 + c1 * 8);
      rv0 = *(const u16x8*)(Vt + base + (size_t)r0 * 2048 + (kv + 1) * 64 + c0 * 8);
      rv1 = *(const u16x8*)(Vt + base + (size_t)r1 * 2048 + (kv + 1) * 64 + c1 * 8);
    }
    const bool doA = (kv <= qtA);

    // S^T for both tiles, shared kf loads
    f32x4 sb[4], sa[4];
#pragma unroll
    for (int nt = 0; nt < 4; ++nt) {
      sb[nt] = (f32x4){0.f, 0.f, 0.f, 0.f};
      sa[nt] = (f32x4){0.f, 0.f, 0.f, 0.f};
    }
#pragma unroll
    for (int nt = 0; nt < 4; ++nt) {
#pragma unroll
      for (int kk = 0; kk < 2; ++kk) {
        const bf16x8 kf = ld_frag(&sK[(nt * 16 + l16) * RS + (kk * 4 + quad) * 8]);
        sb[nt] = MFMA16(kf, qfB[kk], sb[nt]);
        if (doA) sa[nt] = MFMA16(kf, qfA[kk], sa[nt]);
      }
    }
    const int kb = kv * 64 + quad * 4;
    softmax_upd(sb, kb, qgB, mB, lB, oB, sPwB, quad, l16);
    if (doA) softmax_upd(sa, kb, qgA, mA, lA, oA, sPwA, quad, l16);

    bf16x8 pfB[2], pfA[2];
#pragma unroll
    for (int kk = 0; kk < 2; ++kk) {
      pfB[kk] = ld_frag(&sPwB[l16 * RS + kk * 32 + quad * 8]);
      if (doA) pfA[kk] = ld_frag(&sPwA[l16 * RS + kk * 32 + quad * 8]);
    }
#pragma unroll
    for (int dt = 0; dt < 4; ++dt) {
#pragma unroll
      for (int kk = 0; kk < 2; ++kk) {
        const bf16x8 vf = ld_frag(&sV[(dt * 16 + l16) * RS + (kk * 4 + quad) * 8]);
        oB[dt] = MFMA16(vf, pfB[kk], oB[dt]);
        if (doA) oA[dt] = MFMA16(vf, pfA[kk], oA[dt]);
      }
    }
  }

  // epilogue: O^T regs -> y [B,T,H,D]; 4 consecutive d per b64 store
  const int b = bh >> 4, h = bh & 15;
#pragma unroll
  for (int tile = 0; tile < 2; ++tile) {
    const int qt = tile ? qtB : qtA;
    const float linv = 1.f / (tile ? lB : lA);
    const f32x4* o = tile ? oB : oA;
    const int t = qt * 64 + wave * 16 + l16;
#pragma unroll
    for (int dt = 0; dt < 4; ++dt) {
      const f32x4 v = o[dt] * linv;
      *(u16x4*)&Yg[(((size_t)b * 2048 + t) * 16 + h) * 64 + dt * 16 + quad * 4] = pk4(v);
    }
  }
}

extern "C" void kernel_launch(void* const* d_in, const int* in_sizes, int n_in,
                              void* d_out, int out_size, void* d_ws, size_t ws_size,
                              hipStream_t stream) {
  const void* x = d_in[0];      // [4,2048,1024] fp32
  const void* w_qkv = d_in[1];  // [3072,1024] fp32
  const void* w_out = d_in[2];  // [1024,1024] fp32
  float* out = (float*)d_out;   // [4,2048,1024] fp32

  const size_t per = (size_t)4 * 16 * 2048 * 64;  // 8.39M elems
  const size_t nwqkv = (size_t)3072 * 1024;
  const size_t nwout = (size_t)1024 * 1024;
  ushort_t* qws = (ushort_t*)d_ws;   // [B,H,T,D]
  ushort_t* kws = qws + per;         // [B,H,T,D]
  ushort_t* vTws = kws + per;        // [B,H,D,T]
  ushort_t* xyws = vTws + per;       // xbf for gemm1, then y [B,T,H,D]
  ushort_t* wqkvb = xyws + per;      // bf16 w_qkv
  ushort_t* woutb = wqkvb + nwqkv;   // bf16 w_out
  int* flag = (int*)(woutb + nwout);
  const size_t need = (size_t)(4 * per + nwqkv + nwout) * 2 + 16;
  const bool pre = ws_size >= need;  // stable across calls (graph-safe)
  (void)in_sizes; (void)n_in; (void)out_size;

  dim3 blk(256);
  if (!pre) flag = (int*)(xyws + per);
  detect_dtype<<<1, 256, 0, stream>>>((const ushort_t*)x, flag);
  cvt_to_bf16<<<4096, 256, 0, stream>>>(x, xyws, (int)per, flag);
  if (pre) {
    cvt_to_bf16<<<1536, 256, 0, stream>>>(w_qkv, wqkvb, (int)nwqkv, flag);
    cvt_to_bf16<<<512, 256, 0, stream>>>(w_out, woutb, (int)nwout, flag);
    gemm_nt<1><<<dim3(24, 64), blk, 0, stream>>>(xyws, wqkvb, flag, 0, nullptr,
                                                 qws, kws, vTws, 8192, 3072, 1024);
    attn_causal<<<dim3(16, 64), blk, 0, stream>>>(qws, kws, vTws, xyws);
    gemm_nt<0><<<dim3(8, 64), blk, 0, stream>>>(xyws, woutb, flag, 0, out,
                                                nullptr, nullptr, nullptr,
                                                8192, 1024, 1024);
  } else {
    gemm_nt<1><<<dim3(24, 64), blk, 0, stream>>>(xyws, w_qkv, flag, 1, nullptr,
                                                 qws, kws, vTws, 8192, 3072, 1024);
    attn_causal<<<dim3(16, 64), blk, 0, stream>>>(qws, kws, vTws, xyws);
    gemm_nt<0><<<dim3(8, 64), blk, 0, stream>>>(xyws, w_out, flag, 1, out,
                                                nullptr, nullptr, nullptr,
                                                8192, 1024, 1024);
  }
}

// Round 10
// 300.856 us; speedup vs baseline: 1.4825x; 1.4825x over previous
//
#include <hip/hip_runtime.h>
#include <hip/hip_bf16.h>
#include <stdint.h>

// TemporalAttention: x[B,T,C] -> qkv proj -> causal MHA -> out proj.
// B=4 T=2048 C=1024 H=16 D=64. Inputs fp32, output fp32; internal bf16 MFMA.
//
// R9 post-mortem: merged-A/B + prefetch restructure SPILLED under
// __launch_bounds__(256,4) (VGPR clamp 64 vs ~150 live) -> 435MB scratch
// writes, attn 249us. Single change this round: attn launch bounds
// (256,2) so the allocator gets the ~160-VGPR working set (2 blk/CU; the
// merged structure's doubled ILP compensates for fewer waves).

using bf16 = __hip_bfloat16;
typedef __attribute__((ext_vector_type(8))) __bf16 bf16x8;
typedef __attribute__((ext_vector_type(8))) unsigned short u16x8;
typedef __attribute__((ext_vector_type(4))) unsigned short u16x4;
typedef __attribute__((ext_vector_type(4))) float f32x4;
typedef unsigned short ushort_t;

#define MFMA16(a, b, c) __builtin_amdgcn_mfma_f32_16x16x32_bf16((a), (b), (c), 0, 0, 0)
#define EXP2(x) __builtin_amdgcn_exp2f(x)
#define SCL 0.1803368801f  // (1/sqrt(64)) * log2(e)

__device__ __forceinline__ bf16x8 ld_frag(const ushort_t* p) {
  const u16x8 u = *(const u16x8*)p;
  return __builtin_bit_cast(bf16x8, u);
}

__device__ __forceinline__ ushort_t f2bf(float f) {
  return __builtin_bit_cast(ushort_t, __float2bfloat16(f));
}

__device__ __forceinline__ u16x4 pk4(const f32x4 v) {
  u16x4 r;
  r[0] = f2bf(v[0]); r[1] = f2bf(v[1]); r[2] = f2bf(v[2]); r[3] = f2bf(v[3]);
  return r;
}

// async global->LDS, 16B/lane; lds base wave-uniform, lane l -> base+l*16.
__device__ __forceinline__ void gl2lds16(const void* g, void* lds) {
  __builtin_amdgcn_global_load_lds((const __attribute__((address_space(1))) void*)g,
                                   (__attribute__((address_space(3))) void*)lds,
                                   16, 0, 0);
}

// ---------------------------------------------------------------------------
// Dtype detector (hedge; fp32 established). flag=1 -> fp32.
// ---------------------------------------------------------------------------
__global__ void detect_dtype(const ushort_t* __restrict__ x, int* __restrict__ flag) {
  __shared__ int red[256];
  const int tid = threadIdx.x;
  int cnt = 0;
  for (int i = tid; i < 4096; i += 256) {
    const int e = (x[i] & 0x7FFF) >> 7;
    cnt += (e >= 117 && e <= 133) ? 1 : 0;
  }
  red[tid] = cnt;
  __syncthreads();
  for (int s = 128; s > 0; s >>= 1) {
    if (tid < s) red[tid] += red[tid + s];
    __syncthreads();
  }
  if (tid == 0) *flag = (red[0] < 3072) ? 1 : 0;
}

// ---------------------------------------------------------------------------
// fp32 -> bf16 (or copy if flag==0). n multiple of 2048.
// ---------------------------------------------------------------------------
__global__ void cvt_to_bf16(const void* __restrict__ in, ushort_t* __restrict__ out,
                            int n, const int* __restrict__ flag) {
  const int i = (blockIdx.x * 256 + threadIdx.x) * 8;
  if (i >= n) return;
  if (*flag) {
    const float* p = (const float*)in + i;
    const float4 f0 = *(const float4*)p;
    const float4 f1 = *(const float4*)(p + 4);
    u16x8 u;
    u[0] = f2bf(f0.x); u[1] = f2bf(f0.y); u[2] = f2bf(f0.z); u[3] = f2bf(f0.w);
    u[4] = f2bf(f1.x); u[5] = f2bf(f1.y); u[6] = f2bf(f1.z); u[7] = f2bf(f1.w);
    *(u16x8*)(out + i) = u;
  } else {
    *(u16x8*)(out + i) = *(const u16x8*)((const ushort_t*)in + i);
  }
}

// ---------------------------------------------------------------------------
// NT GEMM (unchanged from R7): 128x128 tile, 4 waves 2x2, BK=32, gl2lds.
// EPI==0: fp32 store. EPI==1: scatter q/k [B,H,T,D], V transposed [B,H,D,T].
// ---------------------------------------------------------------------------
template <int EPI>
__global__ __launch_bounds__(256, 2)
void gemm_nt(const ushort_t* __restrict__ A, const void* __restrict__ Bw,
             const int* __restrict__ flag, int bExt,
             float* __restrict__ C0, ushort_t* __restrict__ Qo,
             ushort_t* __restrict__ Ko, ushort_t* __restrict__ Vt,
             int M, int N, int Kd) {
  __shared__ ushort_t sA[128 * 32];
  __shared__ ushort_t sB[128 * 32];
  const int tid = threadIdx.x;
  const int wave = tid >> 6, lane = tid & 63;
  const int quad = lane >> 4, l16 = lane & 15;
  const int wm = wave >> 1, wn = wave & 1;
  const long m0 = (long)blockIdx.y * 128;
  const long n0 = (long)blockIdx.x * 128;
  const int bF = bExt ? *flag : 0;

  f32x4 acc[4][4];
#pragma unroll
  for (int i = 0; i < 4; ++i)
#pragma unroll
    for (int j = 0; j < 4; ++j) acc[i][j] = (f32x4){0.f, 0.f, 0.f, 0.f};

  for (int k0 = 0; k0 < Kd; k0 += 32) {
#pragma unroll
    for (int j = 0; j < 2; ++j) {
      const int chunk = wave * 2 + j;
      const int idx = chunk * 64 + lane;
      const int r = idx >> 2, c = idx & 3;
      gl2lds16(A + (m0 + r) * (long)Kd + k0 + c * 8, (char*)sA + chunk * 1024);
    }
    if (!bF) {
#pragma unroll
      for (int j = 0; j < 2; ++j) {
        const int chunk = wave * 2 + j;
        const int idx = chunk * 64 + lane;
        const int r = idx >> 2, c = idx & 3;
        gl2lds16((const ushort_t*)Bw + (n0 + r) * (long)Kd + k0 + c * 8,
                 (char*)sB + chunk * 1024);
      }
    } else {
#pragma unroll
      for (int t2 = 0; t2 < 2; ++t2) {
        const int idx = t2 * 256 + tid;
        const int r = idx >> 2, c = idx & 3;
        const float* p = (const float*)Bw + (n0 + r) * (long)Kd + k0 + c * 8;
        const float4 f0 = *(const float4*)p;
        const float4 f1 = *(const float4*)(p + 4);
        u16x8 u;
        u[0] = f2bf(f0.x); u[1] = f2bf(f0.y); u[2] = f2bf(f0.z); u[3] = f2bf(f0.w);
        u[4] = f2bf(f1.x); u[5] = f2bf(f1.y); u[6] = f2bf(f1.z); u[7] = f2bf(f1.w);
        *(u16x8*)&sB[r * 32 + c * 8] = u;
      }
    }
    __syncthreads();
    bf16x8 af[4], bfr[4];
#pragma unroll
    for (int i = 0; i < 4; ++i) {
      const int r = wm * 64 + i * 16 + l16;
      af[i] = ld_frag(&sA[r * 32 + quad * 8]);
    }
#pragma unroll
    for (int i = 0; i < 4; ++i) {
      const int r = wn * 64 + i * 16 + l16;
      bfr[i] = ld_frag(&sB[r * 32 + quad * 8]);
    }
#pragma unroll
    for (int i = 0; i < 4; ++i)
#pragma unroll
      for (int j = 0; j < 4; ++j) acc[i][j] = MFMA16(af[i], bfr[j], acc[i][j]);
    __syncthreads();
  }

#pragma unroll
  for (int i = 0; i < 4; ++i) {
#pragma unroll
    for (int j = 0; j < 4; ++j) {
      if (EPI == 0) {
#pragma unroll
        for (int reg = 0; reg < 4; ++reg) {
          const long m = m0 + wm * 64 + i * 16 + quad * 4 + reg;
          const long n = n0 + wn * 64 + j * 16 + l16;
          C0[m * N + n] = acc[i][j][reg];
        }
      } else {
        const long n = n0 + wn * 64 + j * 16 + l16;
        const int which = (int)(n >> 10);
        const int h = (int)((n >> 6) & 15);
        const int d = (int)(n & 63);
        const long mbase = m0 + wm * 64 + i * 16 + quad * 4;
        const long b = mbase >> 11;
        const long tb = mbase & 2047;
        if (which == 2) {
          *(u16x4*)&Vt[((b * 16 + h) * 64 + d) * 2048 + tb] = pk4(acc[i][j]);
        } else {
          ushort_t* dst = (which == 0) ? Qo : Ko;
#pragma unroll
          for (int reg = 0; reg < 4; ++reg)
            dst[((b * 16 + h) * 2048 + tb + reg) * 64 + d] = f2bf(acc[i][j][reg]);
        }
      }
    }
  }
}

// ---------------------------------------------------------------------------
// Flash attention (causal), S^T/O^T, merged A/B pair per kv tile.
// exp2-domain online softmax; per-tile sP regions; register-prefetch K/V.
// launch_bounds (256,2): ~160-VGPR working set must NOT spill (R9 lesson).
// ---------------------------------------------------------------------------
#define RS 72  // LDS row stride in ushorts (64 + 16B pad)

__device__ __forceinline__ void softmax_upd(f32x4 s[4], int kb, int qg,
                                            float& m_i, float& l_i, f32x4* oacc,
                                            ushort_t* sPw, int quad, int l16) {
  float rmax = -1e30f;
#pragma unroll
  for (int nt = 0; nt < 4; ++nt) {
#pragma unroll
    for (int reg = 0; reg < 4; ++reg) {
      float v = s[nt][reg] * SCL;  // log2-domain scaled scores
      if (kb + nt * 16 + reg > qg) v = -1e30f;
      s[nt][reg] = v;
      rmax = fmaxf(rmax, v);
    }
  }
  rmax = fmaxf(rmax, __shfl_xor(rmax, 16, 64));
  rmax = fmaxf(rmax, __shfl_xor(rmax, 32, 64));
  const float mnew = fmaxf(m_i, rmax);
  float rs = 0.f;
#pragma unroll
  for (int nt = 0; nt < 4; ++nt) {
#pragma unroll
    for (int reg = 0; reg < 4; ++reg) {
      const float p = EXP2(s[nt][reg] - mnew);
      s[nt][reg] = p;
      rs += p;
    }
  }
  rs += __shfl_xor(rs, 16, 64);
  rs += __shfl_xor(rs, 32, 64);
  const float alpha = EXP2(m_i - mnew);
  l_i = l_i * alpha + rs;
  m_i = mnew;
#pragma unroll
  for (int dt = 0; dt < 4; ++dt) oacc[dt] *= alpha;
#pragma unroll
  for (int nt = 0; nt < 4; ++nt)
    *(u16x4*)&sPw[l16 * RS + nt * 16 + quad * 4] = pk4(s[nt]);
}

__global__ __launch_bounds__(256, 2)
void attn_causal(const ushort_t* __restrict__ Qg, const ushort_t* __restrict__ Kg,
                 const ushort_t* __restrict__ Vt, ushort_t* __restrict__ Yg) {
  __shared__ ushort_t sK[64 * RS];
  __shared__ ushort_t sV[64 * RS];
  __shared__ ushort_t sPQ[64 * RS];   // Q staging, then per-wave sP for tile A
  __shared__ ushort_t sPB[64 * RS];   // per-wave sP for tile B
  const int tid = threadIdx.x;
  const int wave = tid >> 6, lane = tid & 63;
  const int quad = lane >> 4, l16 = lane & 15;
  const int qx = blockIdx.x, bh = blockIdx.y;
  const int qtA = qx, qtB = 31 - qx;
  const size_t base = (size_t)bh * 2048 * 64;
  ushort_t* sPwA = sPQ + wave * 16 * RS;
  ushort_t* sPwB = sPB + wave * 16 * RS;

  // stage Q tiles -> qfA/qfB frags (sPQ reused)
  bf16x8 qfA[2], qfB[2];
#pragma unroll
  for (int tile = 0; tile < 2; ++tile) {
    const int qt = tile ? qtB : qtA;
#pragma unroll
    for (int t2 = 0; t2 < 2; ++t2) {
      const int idx = t2 * 256 + tid;
      const int r = idx >> 3, c = idx & 7;
      *(u16x8*)&sPQ[r * RS + c * 8] =
          *(const u16x8*)(Qg + base + (size_t)(qt * 64 + r) * 64 + c * 8);
    }
    __syncthreads();
#pragma unroll
    for (int kk = 0; kk < 2; ++kk) {
      const bf16x8 f = ld_frag(&sPQ[(wave * 16 + l16) * RS + (kk * 4 + quad) * 8]);
      if (tile) qfB[kk] = f; else qfA[kk] = f;
    }
    __syncthreads();
  }

  float mA = -1e30f, lA = 0.f, mB = -1e30f, lB = 0.f;
  f32x4 oA[4], oB[4];
#pragma unroll
  for (int dt = 0; dt < 4; ++dt) {
    oA[dt] = (f32x4){0.f, 0.f, 0.f, 0.f};
    oB[dt] = (f32x4){0.f, 0.f, 0.f, 0.f};
  }
  const int qgA = qtA * 64 + wave * 16 + l16;
  const int qgB = qtB * 64 + wave * 16 + l16;

  // prefetch kv=0 staging chunks into registers
  const int r0 = tid >> 3, c0 = tid & 7;            // t2=0
  const int r1 = (256 + tid) >> 3, c1 = tid & 7;    // t2=1
  u16x8 rk0, rk1, rv0, rv1;
  rk0 = *(const u16x8*)(Kg + base + (size_t)r0 * 64 + c0 * 8);
  rk1 = *(const u16x8*)(Kg + base + (size_t)r1 * 64 + c1 * 8);
  rv0 = *(const u16x8*)(Vt + base + (size_t)r0 * 2048 + c0 * 8);
  rv1 = *(const u16x8*)(Vt + base + (size_t)r1 * 2048 + c1 * 8);

  for (int kv = 0; kv <= qtB; ++kv) {
    __syncthreads();  // all waves done reading prev sK/sV
    *(u16x8*)&sK[r0 * RS + c0 * 8] = rk0;
    *(u16x8*)&sK[r1 * RS + c1 * 8] = rk1;
    *(u16x8*)&sV[r0 * RS + c0 * 8] = rv0;
    *(u16x8*)&sV[r1 * RS + c1 * 8] = rv1;
    __syncthreads();
    if (kv < qtB) {  // prefetch next tile; overlaps with compute below
      const size_t kb2 = base + (size_t)(kv + 1) * 64 * 64;
      rk0 = *(const u16x8*)(Kg + kb2 + (size_t)r0 * 64 + c0 * 8);
      rk1 = *(const u16x8*)(Kg + kb2 + (size_t)r1 * 64 + c1 * 8);
      rv0 = *(const u16x8*)(Vt + base + (size_t)r0 * 2048 + (kv + 1) * 64 + c0 * 8);
      rv1 = *(const u16x8*)(Vt + base + (size_t)r1 * 2048 + (kv + 1) * 64 + c1 * 8);
    }
    const bool doA = (kv <= qtA);

    // S^T for both tiles, shared kf loads
    f32x4 sb[4], sa[4];
#pragma unroll
    for (int nt = 0; nt < 4; ++nt) {
      sb[nt] = (f32x4){0.f, 0.f, 0.f, 0.f};
      sa[nt] = (f32x4){0.f, 0.f, 0.f, 0.f};
    }
#pragma unroll
    for (int nt = 0; nt < 4; ++nt) {
#pragma unroll
      for (int kk = 0; kk < 2; ++kk) {
        const bf16x8 kf = ld_frag(&sK[(nt * 16 + l16) * RS + (kk * 4 + quad) * 8]);
        sb[nt] = MFMA16(kf, qfB[kk], sb[nt]);
        if (doA) sa[nt] = MFMA16(kf, qfA[kk], sa[nt]);
      }
    }
    const int kb = kv * 64 + quad * 4;
    softmax_upd(sb, kb, qgB, mB, lB, oB, sPwB, quad, l16);
    if (doA) softmax_upd(sa, kb, qgA, mA, lA, oA, sPwA, quad, l16);

    bf16x8 pfB[2], pfA[2];
#pragma unroll
    for (int kk = 0; kk < 2; ++kk) {
      pfB[kk] = ld_frag(&sPwB[l16 * RS + kk * 32 + quad * 8]);
      if (doA) pfA[kk] = ld_frag(&sPwA[l16 * RS + kk * 32 + quad * 8]);
    }
#pragma unroll
    for (int dt = 0; dt < 4; ++dt) {
#pragma unroll
      for (int kk = 0; kk < 2; ++kk) {
        const bf16x8 vf = ld_frag(&sV[(dt * 16 + l16) * RS + (kk * 4 + quad) * 8]);
        oB[dt] = MFMA16(vf, pfB[kk], oB[dt]);
        if (doA) oA[dt] = MFMA16(vf, pfA[kk], oA[dt]);
      }
    }
  }

  // epilogue: O^T regs -> y [B,T,H,D]; 4 consecutive d per b64 store
  const int b = bh >> 4, h = bh & 15;
#pragma unroll
  for (int tile = 0; tile < 2; ++tile) {
    const int qt = tile ? qtB : qtA;
    const float linv = 1.f / (tile ? lB : lA);
    const f32x4* o = tile ? oB : oA;
    const int t = qt * 64 + wave * 16 + l16;
#pragma unroll
    for (int dt = 0; dt < 4; ++dt) {
      const f32x4 v = o[dt] * linv;
      *(u16x4*)&Yg[(((size_t)b * 2048 + t) * 16 + h) * 64 + dt * 16 + quad * 4] = pk4(v);
    }
  }
}

extern "C" void kernel_launch(void* const* d_in, const int* in_sizes, int n_in,
                              void* d_out, int out_size, void* d_ws, size_t ws_size,
                              hipStream_t stream) {
  const void* x = d_in[0];      // [4,2048,1024] fp32
  const void* w_qkv = d_in[1];  // [3072,1024] fp32
  const void* w_out = d_in[2];  // [1024,1024] fp32
  float* out = (float*)d_out;   // [4,2048,1024] fp32

  const size_t per = (size_t)4 * 16 * 2048 * 64;  // 8.39M elems
  const size_t nwqkv = (size_t)3072 * 1024;
  const size_t nwout = (size_t)1024 * 1024;
  ushort_t* qws = (ushort_t*)d_ws;   // [B,H,T,D]
  ushort_t* kws = qws + per;         // [B,H,T,D]
  ushort_t* vTws = kws + per;        // [B,H,D,T]
  ushort_t* xyws = vTws + per;       // xbf for gemm1, then y [B,T,H,D]
  ushort_t* wqkvb = xyws + per;      // bf16 w_qkv
  ushort_t* woutb = wqkvb + nwqkv;   // bf16 w_out
  int* flag = (int*)(woutb + nwout);
  const size_t need = (size_t)(4 * per + nwqkv + nwout) * 2 + 16;
  const bool pre = ws_size >= need;  // stable across calls (graph-safe)
  (void)in_sizes; (void)n_in; (void)out_size;

  dim3 blk(256);
  if (!pre) flag = (int*)(xyws + per);
  detect_dtype<<<1, 256, 0, stream>>>((const ushort_t*)x, flag);
  cvt_to_bf16<<<4096, 256, 0, stream>>>(x, xyws, (int)per, flag);
  if (pre) {
    cvt_to_bf16<<<1536, 256, 0, stream>>>(w_qkv, wqkvb, (int)nwqkv, flag);
    cvt_to_bf16<<<512, 256, 0, stream>>>(w_out, woutb, (int)nwout, flag);
    gemm_nt<1><<<dim3(24, 64), blk, 0, stream>>>(xyws, wqkvb, flag, 0, nullptr,
                                                 qws, kws, vTws, 8192, 3072, 1024);
    attn_causal<<<dim3(16, 64), blk, 0, stream>>>(qws, kws, vTws, xyws);
    gemm_nt<0><<<dim3(8, 64), blk, 0, stream>>>(xyws, woutb, flag, 0, out,
                                                nullptr, nullptr, nullptr,
                                                8192, 1024, 1024);
  } else {
    gemm_nt<1><<<dim3(24, 64), blk, 0, stream>>>(xyws, w_qkv, flag, 1, nullptr,
                                                 qws, kws, vTws, 8192, 3072, 1024);
    attn_causal<<<dim3(16, 64), blk, 0, stream>>>(qws, kws, vTws, xyws);
    gemm_nt<0><<<dim3(8, 64), blk, 0, stream>>>(xyws, w_out, flag, 1, out,
                                                nullptr, nullptr, nullptr,
                                                8192, 1024, 1024);
  }
}